// Round 1
// baseline (104294.812 us; speedup 1.0000x reference)
//
#include <hip/hip_runtime.h>
#include <math.h>

// Problem constants
#define B_   128
#define T_   20
#define S_   512
#define D_   1024
#define H_   16
#define L_   4
#define KC_  2048   // codebook size
#define DFF_ 4096

// ---------------------------------------------------------------------------
// GEMM:  C[M,N] = A[M,K] * W[N,K]^T (+ bias[N]) (+ bias2[N]) (+ relu)
// Requirements: M % 128 == 0, N % 128 == 0, K % 16 == 0 (all call sites comply)
// 128x128 tile, BK=16, 256 threads, 8x8 per thread as 2x2 quadrants of 4x4.
// ---------------------------------------------------------------------------
__global__ __launch_bounds__(256, 2)
void gemm_nt(const float* __restrict__ A, int lda,
             const float* __restrict__ W, int ldb,
             float* __restrict__ C, int ldc,
             const float* __restrict__ bias,
             const float* __restrict__ bias2,
             int Kd, int relu)
{
    __shared__ float As[16][132];   // +4 pad: LDS stores 2-way max (free)
    __shared__ float Bs[16][132];
    const int tid = threadIdx.x;
    const int m0 = blockIdx.y << 7;
    const int n0 = blockIdx.x << 7;
    const int tx = tid & 15;    // n direction
    const int ty = tid >> 4;    // m direction

    float acc[2][2][4][4];
#pragma unroll
    for (int a = 0; a < 2; ++a)
#pragma unroll
        for (int b = 0; b < 2; ++b)
#pragma unroll
            for (int i = 0; i < 4; ++i)
#pragma unroll
                for (int j = 0; j < 4; ++j) acc[a][b][i][j] = 0.f;

    const int lrow = tid >> 2;          // 0..63
    const int lkk  = (tid & 3) << 2;    // 0,4,8,12
    const float* Ap0 = A + (long)(m0 + lrow)      * lda + lkk;
    const float* Ap1 = A + (long)(m0 + lrow + 64) * lda + lkk;
    const float* Bp0 = W + (long)(n0 + lrow)      * ldb + lkk;
    const float* Bp1 = W + (long)(n0 + lrow + 64) * ldb + lkk;

    for (int k0 = 0; k0 < Kd; k0 += 16) {
        const float4 a0 = *(const float4*)(Ap0 + k0);
        const float4 a1 = *(const float4*)(Ap1 + k0);
        const float4 b0 = *(const float4*)(Bp0 + k0);
        const float4 b1 = *(const float4*)(Bp1 + k0);
        __syncthreads();
        As[lkk + 0][lrow] = a0.x; As[lkk + 1][lrow] = a0.y;
        As[lkk + 2][lrow] = a0.z; As[lkk + 3][lrow] = a0.w;
        As[lkk + 0][lrow + 64] = a1.x; As[lkk + 1][lrow + 64] = a1.y;
        As[lkk + 2][lrow + 64] = a1.z; As[lkk + 3][lrow + 64] = a1.w;
        Bs[lkk + 0][lrow] = b0.x; Bs[lkk + 1][lrow] = b0.y;
        Bs[lkk + 2][lrow] = b0.z; Bs[lkk + 3][lrow] = b0.w;
        Bs[lkk + 0][lrow + 64] = b1.x; Bs[lkk + 1][lrow + 64] = b1.y;
        Bs[lkk + 2][lrow + 64] = b1.z; Bs[lkk + 3][lrow + 64] = b1.w;
        __syncthreads();
#pragma unroll
        for (int kk = 0; kk < 16; ++kk) {
            const float4 aLo = *(const float4*)&As[kk][ty << 2];
            const float4 aHi = *(const float4*)&As[kk][(ty << 2) + 64];
            const float4 bLo = *(const float4*)&Bs[kk][tx << 2];
            const float4 bHi = *(const float4*)&Bs[kk][(tx << 2) + 64];
            const float am[2][4] = {{aLo.x, aLo.y, aLo.z, aLo.w},
                                    {aHi.x, aHi.y, aHi.z, aHi.w}};
            const float bn[2][4] = {{bLo.x, bLo.y, bLo.z, bLo.w},
                                    {bHi.x, bHi.y, bHi.z, bHi.w}};
#pragma unroll
            for (int mi = 0; mi < 2; ++mi)
#pragma unroll
                for (int i = 0; i < 4; ++i) {
                    const float av = am[mi][i];
#pragma unroll
                    for (int ni = 0; ni < 2; ++ni) {
                        acc[mi][ni][i][0] += av * bn[ni][0];
                        acc[mi][ni][i][1] += av * bn[ni][1];
                        acc[mi][ni][i][2] += av * bn[ni][2];
                        acc[mi][ni][i][3] += av * bn[ni][3];
                    }
                }
        }
    }

#pragma unroll
    for (int mi = 0; mi < 2; ++mi)
#pragma unroll
        for (int i = 0; i < 4; ++i) {
            const int m = m0 + (mi << 6) + (ty << 2) + i;
            float* crow = C + (long)m * ldc + n0;
#pragma unroll
            for (int ni = 0; ni < 2; ++ni) {
                const int n = (ni << 6) + (tx << 2);
                float4 v = make_float4(acc[mi][ni][i][0], acc[mi][ni][i][1],
                                       acc[mi][ni][i][2], acc[mi][ni][i][3]);
                if (bias) {
                    v.x += bias[n0 + n];     v.y += bias[n0 + n + 1];
                    v.z += bias[n0 + n + 2]; v.w += bias[n0 + n + 3];
                }
                if (bias2) {
                    v.x += bias2[n0 + n];     v.y += bias2[n0 + n + 1];
                    v.z += bias2[n0 + n + 2]; v.w += bias2[n0 + n + 3];
                }
                if (relu) {
                    v.x = fmaxf(v.x, 0.f); v.y = fmaxf(v.y, 0.f);
                    v.z = fmaxf(v.z, 0.f); v.w = fmaxf(v.w, 0.f);
                }
                *(float4*)(crow + n) = v;
            }
        }
}

// ---------------------------------------------------------------------------
// Attention for hd=64: one wave per (b, h, query-pos). nkeys <= 20.
// q addr = qp + b*q_bs + qj*q_ts + h*64 ; k/v addr = kp/vp + b*kv_bs + j*kv_ts + h*64
// ---------------------------------------------------------------------------
__global__ __launch_bounds__(64)
void attn64(const float* __restrict__ qp, const float* __restrict__ kp,
            const float* __restrict__ vp, float* __restrict__ op,
            int H, long q_bs, long q_ts, long kv_bs, long kv_ts,
            long o_bs, long o_ts, int nk, int causal, float scale)
{
    const int b  = blockIdx.x / H;
    const int h  = blockIdx.x % H;
    const int qj = blockIdx.y;
    const int tid = threadIdx.x;
    __shared__ float sc[32];

    const float qv = qp[(long)b * q_bs + (long)qj * q_ts + h * 64 + tid];
    const int nkeys = causal ? (qj + 1) : nk;
    const long kbase = (long)b * kv_bs + h * 64 + tid;

    for (int j = 0; j < nkeys; ++j) {
        float p = qv * kp[kbase + (long)j * kv_ts];
#pragma unroll
        for (int off = 32; off >= 1; off >>= 1) p += __shfl_xor(p, off);
        if (tid == 0) sc[j] = p * scale;
    }
    __syncthreads();

    const float sval = (tid < nkeys) ? sc[tid] : -INFINITY;
    float mx = sval;
#pragma unroll
    for (int off = 32; off >= 1; off >>= 1) mx = fmaxf(mx, __shfl_xor(mx, off));
    const float e = (tid < nkeys) ? expf(sval - mx) : 0.f;
    float ssum = e;
#pragma unroll
    for (int off = 32; off >= 1; off >>= 1) ssum += __shfl_xor(ssum, off);
    if (tid < nkeys) sc[tid] = e / ssum;
    __syncthreads();

    float acc = 0.f;
    for (int j = 0; j < nkeys; ++j) acc += sc[j] * vp[kbase + (long)j * kv_ts];
    op[(long)b * o_bs + (long)qj * o_ts + h * 64 + tid] = acc;
}

// ---------------------------------------------------------------------------
// LayerNorm with residual: out_row = LN(x_row + h_row) * g + b   (D = 1024)
// One block (256 threads) per row; 4 elems/thread kept in registers.
// ---------------------------------------------------------------------------
__global__ __launch_bounds__(256)
void ln_res(const float* __restrict__ x, const float* __restrict__ hh,
            const float* __restrict__ g, const float* __restrict__ bta,
            float* __restrict__ out)
{
    __shared__ float red[4];
    const int r = blockIdx.x, tid = threadIdx.x;
    const long base = (long)r * D_ + (tid << 2);
    const float4 xv = *(const float4*)(x + base);
    const float4 hv = *(const float4*)(hh + base);
    const float v0 = xv.x + hv.x, v1 = xv.y + hv.y, v2 = xv.z + hv.z, v3 = xv.w + hv.w;

    float s = v0 + v1 + v2 + v3;
#pragma unroll
    for (int off = 32; off >= 1; off >>= 1) s += __shfl_xor(s, off);
    const int wid = tid >> 6, lane = tid & 63;
    if (lane == 0) red[wid] = s;
    __syncthreads();
    const float mean = (red[0] + red[1] + red[2] + red[3]) * (1.f / D_);
    __syncthreads();

    const float d0 = v0 - mean, d1 = v1 - mean, d2 = v2 - mean, d3 = v3 - mean;
    float s2 = d0 * d0 + d1 * d1 + d2 * d2 + d3 * d3;
#pragma unroll
    for (int off = 32; off >= 1; off >>= 1) s2 += __shfl_xor(s2, off);
    if (lane == 0) red[wid] = s2;
    __syncthreads();
    const float var = (red[0] + red[1] + red[2] + red[3]) * (1.f / D_);
    const float rs = 1.f / sqrtf(var + 1e-5f);

    const float4 gv = *(const float4*)(g + (tid << 2));
    const float4 bv = *(const float4*)(bta + (tid << 2));
    float4 o;
    o.x = d0 * rs * gv.x + bv.x; o.y = d1 * rs * gv.y + bv.y;
    o.z = d2 * rs * gv.z + bv.z; o.w = d3 * rs * gv.w + bv.w;
    *(float4*)(out + base) = o;
}

// x[r,:] = se[r,:] + act_emb[actions[r],:] + pos_emb[r % T,:]
__global__ void embed_add(const float* __restrict__ se, const int* __restrict__ actions,
                          const float* __restrict__ act_emb, const float* __restrict__ pos,
                          float* __restrict__ x)
{
    const int r = blockIdx.x, c = threadIdx.x << 2;
    const int t = r % T_;
    const int a = actions[r];
    const float4 sv = *(const float4*)(se + (long)r * D_ + c);
    const float4 av = *(const float4*)(act_emb + (long)a * D_ + c);
    const float4 pv = *(const float4*)(pos + (long)t * D_ + c);
    float4 o;
    o.x = sv.x + av.x + pv.x; o.y = sv.y + av.y + pv.y;
    o.z = sv.z + av.z + pv.z; o.w = sv.w + av.w + pv.w;
    *(float4*)(x + (long)r * D_ + c) = o;
}

// cur[b, 0, :] = se[b, 0, :] + pos_emb[0, :]
__global__ void cur0_init(const float* __restrict__ se, const float* __restrict__ pos,
                          float* __restrict__ cur)
{
    const int b = blockIdx.x, c = threadIdx.x << 2;
    const long base = (long)b * T_ * D_ + c;
    const float4 sv = *(const float4*)(se + base);
    const float4 pv = *(const float4*)(pos + c);
    float4 o; o.x = sv.x + pv.x; o.y = sv.y + pv.y; o.z = sv.z + pv.z; o.w = sv.w + pv.w;
    *(float4*)(cur + base) = o;
}

// y[(b*P+j), :] = cur[(b*T+j), :]  for j < P  (compact prefix gather)
__global__ void assemble_y(const float* __restrict__ cur, float* __restrict__ y, int P)
{
    const int r = blockIdx.x;
    const int b = r / P, j = r - b * P;
    const int c = threadIdx.x << 2;
    *(float4*)(y + (long)r * D_ + c) =
        *(const float4*)(cur + ((long)b * T_ + j) * D_ + c);
}

// quant[r,:] = codebook[idx[r],:]
__global__ void quant_build(const int* __restrict__ idx, const float* __restrict__ cb,
                            float* __restrict__ quant)
{
    const int r = blockIdx.x, c = threadIdx.x << 2;
    const int code = idx[r];
    *(float4*)(quant + (long)r * D_ + c) = *(const float4*)(cb + (long)code * D_ + c);
}

// out[r] = sum(A[r,:]^2) over 1024 cols
__global__ __launch_bounds__(256)
void row_sumsq(const float* __restrict__ A, float* __restrict__ out)
{
    __shared__ float red[4];
    const int r = blockIdx.x, tid = threadIdx.x;
    const float4 v = *(const float4*)(A + (long)r * D_ + (tid << 2));
    float s = v.x * v.x + v.y * v.y + v.z * v.z + v.w * v.w;
#pragma unroll
    for (int off = 32; off >= 1; off >>= 1) s += __shfl_xor(s, off);
    const int wid = tid >> 6, lane = tid & 63;
    if (lane == 0) red[wid] = s;
    __syncthreads();
    if (tid == 0) out[r] = red[0] + red[1] + red[2] + red[3];
}

// dist_j = (sum(x_r^2) - 2*dot[r,j]) + c2[j], numpy elementwise order in fp32.
// argmin with lowest-index tie-break (matches jnp.argmax-first on the softmax).
__global__ __launch_bounds__(256)
void vq_argmin(const float* __restrict__ x, const float* __restrict__ dot,
               const float* __restrict__ c2, int* __restrict__ idx_i,
               float* __restrict__ idx_f)
{
    __shared__ float red[4];
    __shared__ float redv[4];
    __shared__ int   redi[4];
    const int r = blockIdx.x, tid = threadIdx.x;
    const float4 v = *(const float4*)(x + (long)r * D_ + (tid << 2));
    float s = v.x * v.x + v.y * v.y + v.z * v.z + v.w * v.w;
#pragma unroll
    for (int off = 32; off >= 1; off >>= 1) s += __shfl_xor(s, off);
    const int wid = tid >> 6, lane = tid & 63;
    if (lane == 0) red[wid] = s;
    __syncthreads();
    const float a = red[0] + red[1] + red[2] + red[3];

    float best = 3.4e38f; int bidx = 0;
    const float* dr = dot + (long)r * KC_;
    for (int j = tid; j < KC_; j += 256) {
        const float d = (a - 2.f * dr[j]) + c2[j];
        if (d < best) { best = d; bidx = j; }
    }
#pragma unroll
    for (int off = 32; off >= 1; off >>= 1) {
        const float ob = __shfl_xor(best, off);
        const int   oi = __shfl_xor(bidx, off);
        if (ob < best || (ob == best && oi < bidx)) { best = ob; bidx = oi; }
    }
    if (lane == 0) { redv[wid] = best; redi[wid] = bidx; }
    __syncthreads();
    if (tid == 0) {
        for (int w2 = 1; w2 < 4; ++w2)
            if (redv[w2] < best || (redv[w2] == best && redi[w2] < bidx)) {
                best = redv[w2]; bidx = redi[w2];
            }
        idx_i[r] = bidx;
        idx_f[r] = (float)bidx;
    }
}

__global__ void zero_f(float* p) { p[0] = 0.f; }

__global__ __launch_bounds__(256)
void sq_diff_partial(const float* __restrict__ x, const float* __restrict__ q,
                     float* __restrict__ accum)
{
    __shared__ float red[4];
    const int r = blockIdx.x, tid = threadIdx.x;
    const long base = (long)r * D_ + (tid << 2);
    const float4 xv = *(const float4*)(x + base);
    const float4 qv = *(const float4*)(q + base);
    const float d0 = xv.x - qv.x, d1 = xv.y - qv.y, d2 = xv.z - qv.z, d3 = xv.w - qv.w;
    float s = d0 * d0 + d1 * d1 + d2 * d2 + d3 * d3;
#pragma unroll
    for (int off = 32; off >= 1; off >>= 1) s += __shfl_xor(s, off);
    const int wid = tid >> 6, lane = tid & 63;
    if (lane == 0) red[wid] = s;
    __syncthreads();
    if (tid == 0) atomicAdd(accum, red[0] + red[1] + red[2] + red[3]);
}

__global__ void loss_final(const float* __restrict__ accum, float* __restrict__ out)
{
    // vq_loss = BETA*mean + mean = 2*mean over B*T*D elements (BETA=1)
    out[0] = 2.f * accum[0] * (1.f / (float)((long)B_ * T_ * D_));
}

// ---------------------------------------------------------------------------
extern "C" void kernel_launch(void* const* d_in, const int* in_sizes, int n_in,
                              void* d_out, int out_size, void* d_ws, size_t ws_size,
                              hipStream_t stream)
{
    const float* states      = (const float*)d_in[0];
    const int*   actions     = (const int*)  d_in[1];
    const float* enc_W       = (const float*)d_in[2];
    const float* enc_b       = (const float*)d_in[3];
    const float* act_emb     = (const float*)d_in[4];
    const float* pos_emb     = (const float*)d_in[5];
    const float* enc_qkv_w   = (const float*)d_in[6];
    const float* enc_qkv_b   = (const float*)d_in[7];
    const float* enc_out_w   = (const float*)d_in[8];
    const float* enc_out_b   = (const float*)d_in[9];
    const float* enc_ln1_g   = (const float*)d_in[10];
    const float* enc_ln1_b   = (const float*)d_in[11];
    const float* enc_ln2_g   = (const float*)d_in[12];
    const float* enc_ln2_b   = (const float*)d_in[13];
    const float* enc_ff1_w   = (const float*)d_in[14];
    const float* enc_ff1_b   = (const float*)d_in[15];
    const float* enc_ff2_w   = (const float*)d_in[16];
    const float* enc_ff2_b   = (const float*)d_in[17];
    const float* dec_sa_qkv_w= (const float*)d_in[18];
    const float* dec_sa_qkv_b= (const float*)d_in[19];
    const float* dec_sa_out_w= (const float*)d_in[20];
    const float* dec_sa_out_b= (const float*)d_in[21];
    const float* dec_ca_qkv_w= (const float*)d_in[22];
    const float* dec_ca_qkv_b= (const float*)d_in[23];
    const float* dec_ca_out_w= (const float*)d_in[24];
    const float* dec_ca_out_b= (const float*)d_in[25];
    const float* dec_ln1_g   = (const float*)d_in[26];
    const float* dec_ln1_b   = (const float*)d_in[27];
    const float* dec_ln2_g   = (const float*)d_in[28];
    const float* dec_ln2_b   = (const float*)d_in[29];
    const float* dec_ln3_g   = (const float*)d_in[30];
    const float* dec_ln3_b   = (const float*)d_in[31];
    const float* dec_ff1_w   = (const float*)d_in[32];
    const float* dec_ff1_b   = (const float*)d_in[33];
    const float* dec_ff2_w   = (const float*)d_in[34];
    const float* dec_ff2_b   = (const float*)d_in[35];
    const float* codebook    = (const float*)d_in[36];
    const float* rec_W       = (const float*)d_in[37];
    const float* rec_b       = (const float*)d_in[38];

    float* out      = (float*)d_out;
    float* pred     = out;                       // [128, 19, 512]
    float* loss_out = out + (long)B_ * (T_ - 1) * S_;   // 1245184
    float* idx_out  = loss_out + 1;              // 2560 floats

    const long NTOK = (long)B_ * T_;             // 2560
    const long ROW  = NTOK * D_;                 // 2,621,440 floats

    float* w    = (float*)d_ws;
    float* se   = w;  w += ROW;
    float* xbuf = w;  w += ROW;
    float* big  = w;  w += NTOK * DFF_;          // 10,485,760 (also VQ-dot / dec qkv / CA-attn-out / FFN hidden)
    float* bufa = w;  w += ROW;
    float* bufb = w;  w += ROW;
    float* quant= w;  w += ROW;
    float* cur  = w;  w += ROW;                  // dec_in + pos_emb, persistent per call
    float* ybuf = w;  w += ROW;
    float* memKV= w;  w += (long)L_ * NTOK * 2 * D_;   // 20,971,520
    float* c2   = w;  w += KC_;
    float* accum= w;  w += 1;
    int*   idx_i= (int*)w;                       // 2560 ints
    const size_t need = (size_t)((char*)(idx_i + NTOK) - (char*)d_ws);
    if (ws_size < need) return;  // workspace too small -> fail loudly (output stays poisoned)

    auto gemm = [&](const float* A, int lda, const float* Wt, int Kd, int N, int M,
                    float* C, int ldc, const float* bias, const float* bias2, int relu) {
        dim3 g(N >> 7, M >> 7);
        gemm_nt<<<g, 256, 0, stream>>>(A, lda, Wt, Kd, C, ldc, bias, bias2, Kd, relu);
    };
    auto attn = [&](const float* qp, const float* kp, const float* vp, float* op,
                    long q_bs, long q_ts, long kv_bs, long kv_ts,
                    long o_bs, long o_ts, int nq, int nk, int causal) {
        dim3 g(B_ * H_, nq);
        attn64<<<g, 64, 0, stream>>>(qp, kp, vp, op, H_, q_bs, q_ts, kv_bs, kv_ts,
                                     o_bs, o_ts, nk, causal, 0.125f);
    };

    // ======================= Encoder =======================
    gemm(states, S_, enc_W, S_, D_, (int)NTOK, se, D_, enc_b, nullptr, 0);
    embed_add<<<(int)NTOK, 256, 0, stream>>>(se, actions, act_emb, pos_emb, xbuf);

    for (int i = 0; i < L_; ++i) {
        gemm(xbuf, D_, enc_qkv_w + (long)i * 3 * D_ * D_, D_, 3 * D_, (int)NTOK,
             big, 3 * D_, enc_qkv_b + (long)i * 3 * D_, nullptr, 0);
        attn(big, big + D_, big + 2 * D_, bufa,
             (long)T_ * 3 * D_, 3 * D_, (long)T_ * 3 * D_, 3 * D_,
             (long)T_ * D_, D_, T_, T_, 0);
        gemm(bufa, D_, enc_out_w + (long)i * D_ * D_, D_, D_, (int)NTOK,
             bufb, D_, enc_out_b + i * D_, nullptr, 0);
        ln_res<<<(int)NTOK, 256, 0, stream>>>(xbuf, bufb, enc_ln1_g + i * D_, enc_ln1_b + i * D_, xbuf);
        gemm(xbuf, D_, enc_ff1_w + (long)i * DFF_ * D_, D_, DFF_, (int)NTOK,
             big, DFF_, enc_ff1_b + i * DFF_, nullptr, 1);
        gemm(big, DFF_, enc_ff2_w + (long)i * D_ * DFF_, DFF_, D_, (int)NTOK,
             bufb, D_, enc_ff2_b + i * D_, nullptr, 0);
        ln_res<<<(int)NTOK, 256, 0, stream>>>(xbuf, bufb, enc_ln2_g + i * D_, enc_ln2_b + i * D_, xbuf);
    }

    // ======================= VQ =======================
    row_sumsq<<<KC_, 256, 0, stream>>>(codebook, c2);
    gemm(xbuf, D_, codebook, D_, KC_, (int)NTOK, big, KC_, nullptr, nullptr, 0);  // x @ cb^T
    vq_argmin<<<(int)NTOK, 256, 0, stream>>>(xbuf, big, c2, idx_i, idx_out);
    quant_build<<<(int)NTOK, 256, 0, stream>>>(idx_i, codebook, quant);
    zero_f<<<1, 1, 0, stream>>>(accum);
    sq_diff_partial<<<(int)NTOK, 256, 0, stream>>>(xbuf, quant, accum);
    loss_final<<<1, 1, 0, stream>>>(accum, loss_out);

    // ============ Decoder: precompute cross-attn K/V (quant is fixed) ============
    for (int i = 0; i < L_; ++i) {
        const float* wkv = dec_ca_qkv_w + (long)i * 3 * D_ * D_ + (long)D_ * D_;  // rows D..3D
        const float* bkv = dec_ca_qkv_b + (long)i * 3 * D_ + D_;
        gemm(quant, D_, wkv, D_, 2 * D_, (int)NTOK,
             memKV + (long)i * NTOK * 2 * D_, 2 * D_, bkv, nullptr, 0);
    }
    cur0_init<<<B_, 256, 0, stream>>>(se, pos_emb, cur);

    // ============ Decoder: 19 autoregressive steps ============
    for (int t = 0; t < T_ - 1; ++t) {
        const int P = t + 1;
        const int M = B_ * P;
        assemble_y<<<M, 256, 0, stream>>>(cur, ybuf, P);

        for (int i = 0; i < L_; ++i) {
            // --- causal self-attention ---
            gemm(ybuf, D_, dec_sa_qkv_w + (long)i * 3 * D_ * D_, D_, 3 * D_, M,
                 big, 3 * D_, dec_sa_qkv_b + (long)i * 3 * D_, nullptr, 0);
            attn(big, big + D_, big + 2 * D_, bufa,
                 (long)P * 3 * D_, 3 * D_, (long)P * 3 * D_, 3 * D_,
                 (long)P * D_, D_, P, P, 1);
            gemm(bufa, D_, dec_sa_out_w + (long)i * D_ * D_, D_, D_, M,
                 bufb, D_, dec_sa_out_b + i * D_, nullptr, 0);
            ln_res<<<M, 256, 0, stream>>>(ybuf, bufb, dec_ln1_g + i * D_, dec_ln1_b + i * D_, ybuf);

            // --- cross-attention (memory = quant[:, :P] via precomputed memKV) ---
            gemm(ybuf, D_, dec_ca_qkv_w + (long)i * 3 * D_ * D_, D_, D_, M,
                 bufa, D_, dec_ca_qkv_b + (long)i * 3 * D_, nullptr, 0);  // q proj only
            const float* mkv = memKV + (long)i * NTOK * 2 * D_;
            attn(bufa, mkv, mkv + D_, big,
                 (long)P * D_, D_, (long)T_ * 2 * D_, 2 * D_,
                 (long)P * D_, D_, P, P, 0);
            gemm(big, D_, dec_ca_out_w + (long)i * D_ * D_, D_, D_, M,
                 bufb, D_, dec_ca_out_b + i * D_, nullptr, 0);
            ln_res<<<M, 256, 0, stream>>>(ybuf, bufb, dec_ln2_g + i * D_, dec_ln2_b + i * D_, ybuf);

            // --- FFN ---
            gemm(ybuf, D_, dec_ff1_w + (long)i * DFF_ * D_, D_, DFF_, M,
                 big, DFF_, dec_ff1_b + i * DFF_, nullptr, 1);
            gemm(big, DFF_, dec_ff2_w + (long)i * D_ * DFF_, DFF_, D_, M,
                 bufb, D_, dec_ff2_b + i * D_, nullptr, 0);
            ln_res<<<M, 256, 0, stream>>>(ybuf, bufb, dec_ln3_g + i * D_, dec_ln3_b + i * D_, ybuf);
        }

        // preds[t] = y[:, -1] @ rec_W^T + rec_b   -> pred[:, t, :]
        gemm(ybuf + (long)(P - 1) * D_, P * D_, rec_W, D_, S_, B_,
             pred + (long)t * S_, (T_ - 1) * S_, rec_b, nullptr, 0);

        // dec_in[:, t+1] = preds[t] @ enc_W^T + enc_b ; cur adds pos_emb[t+1]
        if (t < T_ - 2)
            gemm(pred + (long)t * S_, (T_ - 1) * S_, enc_W, S_, D_, B_,
                 cur + (long)(t + 1) * D_, T_ * D_, enc_b, pos_emb + (long)(t + 1) * D_, 0);
    }
}

// Round 2
// 53473.596 us; speedup vs baseline: 1.9504x; 1.9504x over previous
//
#include <hip/hip_runtime.h>
#include <math.h>

// Problem constants
#define B_   128
#define T_   20
#define S_   512
#define D_   1024
#define H_   16
#define L_   4
#define KC_  2048   // codebook size
#define DFF_ 4096

typedef __attribute__((ext_vector_type(8))) short bf16x8;   // 8 bf16 (4 VGPRs)
typedef __attribute__((ext_vector_type(4))) float f32x4;

__device__ __forceinline__ unsigned short f2bf_rne(float f) {
    unsigned u = __float_as_uint(f);
    u += 0x7fffu + ((u >> 16) & 1u);
    return (unsigned short)(u >> 16);
}
__device__ __forceinline__ unsigned pack2(float a, float b) {
    return (unsigned)f2bf_rne(a) | ((unsigned)f2bf_rne(b) << 16);
}

// ---------------------------------------------------------------------------
// fp32 GEMM (encoder + VQ path — bit-stable vs round 1):
// C[M,N] = A[M,K] * W[N,K]^T (+bias)(+bias2)(+relu); M%128==0, N%128==0, K%16==0
// ---------------------------------------------------------------------------
__global__ __launch_bounds__(256, 2)
void gemm_nt(const float* __restrict__ A, int lda,
             const float* __restrict__ W, int ldb,
             float* __restrict__ C, int ldc,
             const float* __restrict__ bias,
             const float* __restrict__ bias2,
             int Kd, int relu)
{
    __shared__ float As[16][132];
    __shared__ float Bs[16][132];
    const int tid = threadIdx.x;
    const int m0 = blockIdx.y << 7;
    const int n0 = blockIdx.x << 7;
    const int tx = tid & 15;
    const int ty = tid >> 4;

    float acc[2][2][4][4];
#pragma unroll
    for (int a = 0; a < 2; ++a)
#pragma unroll
        for (int b = 0; b < 2; ++b)
#pragma unroll
            for (int i = 0; i < 4; ++i)
#pragma unroll
                for (int j = 0; j < 4; ++j) acc[a][b][i][j] = 0.f;

    const int lrow = tid >> 2;
    const int lkk  = (tid & 3) << 2;
    const float* Ap0 = A + (long)(m0 + lrow)      * lda + lkk;
    const float* Ap1 = A + (long)(m0 + lrow + 64) * lda + lkk;
    const float* Bp0 = W + (long)(n0 + lrow)      * ldb + lkk;
    const float* Bp1 = W + (long)(n0 + lrow + 64) * ldb + lkk;

    for (int k0 = 0; k0 < Kd; k0 += 16) {
        const float4 a0 = *(const float4*)(Ap0 + k0);
        const float4 a1 = *(const float4*)(Ap1 + k0);
        const float4 b0 = *(const float4*)(Bp0 + k0);
        const float4 b1 = *(const float4*)(Bp1 + k0);
        __syncthreads();
        As[lkk + 0][lrow] = a0.x; As[lkk + 1][lrow] = a0.y;
        As[lkk + 2][lrow] = a0.z; As[lkk + 3][lrow] = a0.w;
        As[lkk + 0][lrow + 64] = a1.x; As[lkk + 1][lrow + 64] = a1.y;
        As[lkk + 2][lrow + 64] = a1.z; As[lkk + 3][lrow + 64] = a1.w;
        Bs[lkk + 0][lrow] = b0.x; Bs[lkk + 1][lrow] = b0.y;
        Bs[lkk + 2][lrow] = b0.z; Bs[lkk + 3][lrow] = b0.w;
        Bs[lkk + 0][lrow + 64] = b1.x; Bs[lkk + 1][lrow + 64] = b1.y;
        Bs[lkk + 2][lrow + 64] = b1.z; Bs[lkk + 3][lrow + 64] = b1.w;
        __syncthreads();
#pragma unroll
        for (int kk = 0; kk < 16; ++kk) {
            const float4 aLo = *(const float4*)&As[kk][ty << 2];
            const float4 aHi = *(const float4*)&As[kk][(ty << 2) + 64];
            const float4 bLo = *(const float4*)&Bs[kk][tx << 2];
            const float4 bHi = *(const float4*)&Bs[kk][(tx << 2) + 64];
            const float am[2][4] = {{aLo.x, aLo.y, aLo.z, aLo.w},
                                    {aHi.x, aHi.y, aHi.z, aHi.w}};
            const float bn[2][4] = {{bLo.x, bLo.y, bLo.z, bLo.w},
                                    {bHi.x, bHi.y, bHi.z, bHi.w}};
#pragma unroll
            for (int mi = 0; mi < 2; ++mi)
#pragma unroll
                for (int i = 0; i < 4; ++i) {
                    const float av = am[mi][i];
#pragma unroll
                    for (int ni = 0; ni < 2; ++ni) {
                        acc[mi][ni][i][0] += av * bn[ni][0];
                        acc[mi][ni][i][1] += av * bn[ni][1];
                        acc[mi][ni][i][2] += av * bn[ni][2];
                        acc[mi][ni][i][3] += av * bn[ni][3];
                    }
                }
        }
    }

#pragma unroll
    for (int mi = 0; mi < 2; ++mi)
#pragma unroll
        for (int i = 0; i < 4; ++i) {
            const int m = m0 + (mi << 6) + (ty << 2) + i;
            float* crow = C + (long)m * ldc + n0;
#pragma unroll
            for (int ni = 0; ni < 2; ++ni) {
                const int n = (ni << 6) + (tx << 2);
                float4 v = make_float4(acc[mi][ni][i][0], acc[mi][ni][i][1],
                                       acc[mi][ni][i][2], acc[mi][ni][i][3]);
                if (bias) {
                    v.x += bias[n0 + n];     v.y += bias[n0 + n + 1];
                    v.z += bias[n0 + n + 2]; v.w += bias[n0 + n + 3];
                }
                if (bias2) {
                    v.x += bias2[n0 + n];     v.y += bias2[n0 + n + 1];
                    v.z += bias2[n0 + n + 2]; v.w += bias2[n0 + n + 3];
                }
                if (relu) {
                    v.x = fmaxf(v.x, 0.f); v.y = fmaxf(v.y, 0.f);
                    v.z = fmaxf(v.z, 0.f); v.w = fmaxf(v.w, 0.f);
                }
                *(float4*)(crow + n) = v;
            }
        }
}

// ---------------------------------------------------------------------------
// bf16 MFMA GEMM (decoder path): C[M,N] = A_f32[M,K] * Wbf16[N,K]^T
// A converted fp32->bf16 (RNE) during LDS staging; fp32 accumulation.
// 128x128 tile, BK=64, 4 waves, each wave 64x64 via 4x4 of 16x16x32 MFMA.
// LDS rows padded to 72 bf16 (144B stride -> 2-way bank aliasing = free).
// Fragment layouts per learn_hip m89/m91 (verified on gfx950).
// ---------------------------------------------------------------------------
#define LDSP 72

__global__ __launch_bounds__(256, 2)
void gemm_bf16(const float* __restrict__ A, int lda,
               const unsigned short* __restrict__ W, int ldb,
               float* __restrict__ C, int ldc,
               const float* __restrict__ bias,
               const float* __restrict__ bias2,
               int Kd, int relu)
{
    __shared__ unsigned short As[128 * LDSP];
    __shared__ unsigned short Bs[128 * LDSP];
    const int tid = threadIdx.x;
    const int m0 = blockIdx.y << 7;
    const int n0 = blockIdx.x << 7;
    const int wave = tid >> 6;
    const int lane = tid & 63;
    const int wm = (wave >> 1) << 6;    // 0 / 64
    const int wn = (wave & 1) << 6;     // 0 / 64
    const int lrow = lane & 15;
    const int q = lane >> 4;

    const int srow  = tid >> 1;         // 0..127
    const int shalf = (tid & 1) << 5;   // 0 / 32 (bf16 elems)

    const float*          Ap  = A + (long)(m0 + srow) * lda + shalf;
    const unsigned short* Bp  = W + (long)(n0 + srow) * ldb + shalf;
    unsigned short* AsW = &As[srow * LDSP + shalf];
    unsigned short* BsW = &Bs[srow * LDSP + shalf];

    f32x4 acc[4][4];
#pragma unroll
    for (int i = 0; i < 4; ++i)
#pragma unroll
        for (int j = 0; j < 4; ++j) acc[i][j] = (f32x4){0.f, 0.f, 0.f, 0.f};

    for (int k0 = 0; k0 < Kd; k0 += 64) {
        float4 a4[8];
#pragma unroll
        for (int i = 0; i < 8; ++i) a4[i] = *(const float4*)(Ap + k0 + i * 4);
        uint4 bv[4];
#pragma unroll
        for (int i = 0; i < 4; ++i) bv[i] = *(const uint4*)(Bp + k0 + i * 8);

        __syncthreads();
#pragma unroll
        for (int i = 0; i < 4; ++i) {
            uint4 wv;
            wv.x = pack2(a4[2 * i].x,     a4[2 * i].y);
            wv.y = pack2(a4[2 * i].z,     a4[2 * i].w);
            wv.z = pack2(a4[2 * i + 1].x, a4[2 * i + 1].y);
            wv.w = pack2(a4[2 * i + 1].z, a4[2 * i + 1].w);
            ((uint4*)AsW)[i] = wv;
        }
#pragma unroll
        for (int i = 0; i < 4; ++i) ((uint4*)BsW)[i] = bv[i];
        __syncthreads();

#pragma unroll
        for (int kk = 0; kk < 2; ++kk) {
            bf16x8 af[4], bfr[4];
#pragma unroll
            for (int mi = 0; mi < 4; ++mi)
                af[mi] = *(const bf16x8*)&As[(wm + mi * 16 + lrow) * LDSP + kk * 32 + q * 8];
#pragma unroll
            for (int ni = 0; ni < 4; ++ni)
                bfr[ni] = *(const bf16x8*)&Bs[(wn + ni * 16 + lrow) * LDSP + kk * 32 + q * 8];
#pragma unroll
            for (int mi = 0; mi < 4; ++mi)
#pragma unroll
                for (int ni = 0; ni < 4; ++ni)
                    acc[mi][ni] = __builtin_amdgcn_mfma_f32_16x16x32_bf16(
                        af[mi], bfr[ni], acc[mi][ni], 0, 0, 0);
        }
    }

    // C/D layout: col = lane&15, row = (lane>>4)*4 + reg   [m89/m91]
#pragma unroll
    for (int mi = 0; mi < 4; ++mi) {
#pragma unroll
        for (int r = 0; r < 4; ++r) {
            const int m = m0 + wm + mi * 16 + q * 4 + r;
            float* crow = C + (long)m * ldc + n0 + wn;
#pragma unroll
            for (int ni = 0; ni < 4; ++ni) {
                const int n = ni * 16 + lrow;
                float v = acc[mi][ni][r];
                if (bias)  v += bias[n0 + wn + n];
                if (bias2) v += bias2[n0 + wn + n];
                if (relu)  v = fmaxf(v, 0.f);
                crow[n] = v;
            }
        }
    }
}

// fp32 -> bf16 (RNE) bulk convert; n4 = n/4 float4 groups
__global__ __launch_bounds__(256)
void convert_f2bf(const float* __restrict__ src, unsigned short* __restrict__ dst, long n4)
{
    const long i = (long)blockIdx.x * 256 + threadIdx.x;
    if (i < n4) {
        const float4 v = ((const float4*)src)[i];
        uint2 o;
        o.x = pack2(v.x, v.y);
        o.y = pack2(v.z, v.w);
        ((uint2*)dst)[i] = o;
    }
}

// ---------------------------------------------------------------------------
// Attention for hd=64: one wave per (b, h, query-pos). nkeys <= 20.
// ---------------------------------------------------------------------------
__global__ __launch_bounds__(64)
void attn64(const float* __restrict__ qp, const float* __restrict__ kp,
            const float* __restrict__ vp, float* __restrict__ op,
            int H, long q_bs, long q_ts, long kv_bs, long kv_ts,
            long o_bs, long o_ts, int nk, int causal, float scale)
{
    const int b  = blockIdx.x / H;
    const int h  = blockIdx.x % H;
    const int qj = blockIdx.y;
    const int tid = threadIdx.x;
    __shared__ float sc[32];

    const float qv = qp[(long)b * q_bs + (long)qj * q_ts + h * 64 + tid];
    const int nkeys = causal ? (qj + 1) : nk;
    const long kbase = (long)b * kv_bs + h * 64 + tid;

    for (int j = 0; j < nkeys; ++j) {
        float p = qv * kp[kbase + (long)j * kv_ts];
#pragma unroll
        for (int off = 32; off >= 1; off >>= 1) p += __shfl_xor(p, off);
        if (tid == 0) sc[j] = p * scale;
    }
    __syncthreads();

    const float sval = (tid < nkeys) ? sc[tid] : -INFINITY;
    float mx = sval;
#pragma unroll
    for (int off = 32; off >= 1; off >>= 1) mx = fmaxf(mx, __shfl_xor(mx, off));
    const float e = (tid < nkeys) ? expf(sval - mx) : 0.f;
    float ssum = e;
#pragma unroll
    for (int off = 32; off >= 1; off >>= 1) ssum += __shfl_xor(ssum, off);
    if (tid < nkeys) sc[tid] = e / ssum;
    __syncthreads();

    float acc = 0.f;
    for (int j = 0; j < nkeys; ++j) acc += sc[j] * vp[kbase + (long)j * kv_ts];
    op[(long)b * o_bs + (long)qj * o_ts + h * 64 + tid] = acc;
}

// ---------------------------------------------------------------------------
// LayerNorm with residual
// ---------------------------------------------------------------------------
__global__ __launch_bounds__(256)
void ln_res(const float* __restrict__ x, const float* __restrict__ hh,
            const float* __restrict__ g, const float* __restrict__ bta,
            float* __restrict__ out)
{
    __shared__ float red[4];
    const int r = blockIdx.x, tid = threadIdx.x;
    const long base = (long)r * D_ + (tid << 2);
    const float4 xv = *(const float4*)(x + base);
    const float4 hv = *(const float4*)(hh + base);
    const float v0 = xv.x + hv.x, v1 = xv.y + hv.y, v2 = xv.z + hv.z, v3 = xv.w + hv.w;

    float s = v0 + v1 + v2 + v3;
#pragma unroll
    for (int off = 32; off >= 1; off >>= 1) s += __shfl_xor(s, off);
    const int wid = tid >> 6, lane = tid & 63;
    if (lane == 0) red[wid] = s;
    __syncthreads();
    const float mean = (red[0] + red[1] + red[2] + red[3]) * (1.f / D_);
    __syncthreads();

    const float d0 = v0 - mean, d1 = v1 - mean, d2 = v2 - mean, d3 = v3 - mean;
    float s2 = d0 * d0 + d1 * d1 + d2 * d2 + d3 * d3;
#pragma unroll
    for (int off = 32; off >= 1; off >>= 1) s2 += __shfl_xor(s2, off);
    if (lane == 0) red[wid] = s2;
    __syncthreads();
    const float var = (red[0] + red[1] + red[2] + red[3]) * (1.f / D_);
    const float rs = 1.f / sqrtf(var + 1e-5f);

    const float4 gv = *(const float4*)(g + (tid << 2));
    const float4 bv = *(const float4*)(bta + (tid << 2));
    float4 o;
    o.x = d0 * rs * gv.x + bv.x; o.y = d1 * rs * gv.y + bv.y;
    o.z = d2 * rs * gv.z + bv.z; o.w = d3 * rs * gv.w + bv.w;
    *(float4*)(out + base) = o;
}

__global__ void embed_add(const float* __restrict__ se, const int* __restrict__ actions,
                          const float* __restrict__ act_emb, const float* __restrict__ pos,
                          float* __restrict__ x)
{
    const int r = blockIdx.x, c = threadIdx.x << 2;
    const int t = r % T_;
    const int a = actions[r];
    const float4 sv = *(const float4*)(se + (long)r * D_ + c);
    const float4 av = *(const float4*)(act_emb + (long)a * D_ + c);
    const float4 pv = *(const float4*)(pos + (long)t * D_ + c);
    float4 o;
    o.x = sv.x + av.x + pv.x; o.y = sv.y + av.y + pv.y;
    o.z = sv.z + av.z + pv.z; o.w = sv.w + av.w + pv.w;
    *(float4*)(x + (long)r * D_ + c) = o;
}

__global__ void cur0_init(const float* __restrict__ se, const float* __restrict__ pos,
                          float* __restrict__ cur)
{
    const int b = blockIdx.x, c = threadIdx.x << 2;
    const long base = (long)b * T_ * D_ + c;
    const float4 sv = *(const float4*)(se + base);
    const float4 pv = *(const float4*)(pos + c);
    float4 o; o.x = sv.x + pv.x; o.y = sv.y + pv.y; o.z = sv.z + pv.z; o.w = sv.w + pv.w;
    *(float4*)(cur + base) = o;
}

__global__ void assemble_y(const float* __restrict__ cur, float* __restrict__ y, int P)
{
    const int r = blockIdx.x;
    const int b = r / P, j = r - b * P;
    const int c = threadIdx.x << 2;
    *(float4*)(y + (long)r * D_ + c) =
        *(const float4*)(cur + ((long)b * T_ + j) * D_ + c);
}

__global__ void quant_build(const int* __restrict__ idx, const float* __restrict__ cb,
                            float* __restrict__ quant)
{
    const int r = blockIdx.x, c = threadIdx.x << 2;
    const int code = idx[r];
    *(float4*)(quant + (long)r * D_ + c) = *(const float4*)(cb + (long)code * D_ + c);
}

__global__ __launch_bounds__(256)
void row_sumsq(const float* __restrict__ A, float* __restrict__ out)
{
    __shared__ float red[4];
    const int r = blockIdx.x, tid = threadIdx.x;
    const float4 v = *(const float4*)(A + (long)r * D_ + (tid << 2));
    float s = v.x * v.x + v.y * v.y + v.z * v.z + v.w * v.w;
#pragma unroll
    for (int off = 32; off >= 1; off >>= 1) s += __shfl_xor(s, off);
    const int wid = tid >> 6, lane = tid & 63;
    if (lane == 0) red[wid] = s;
    __syncthreads();
    if (tid == 0) out[r] = red[0] + red[1] + red[2] + red[3];
}

__global__ __launch_bounds__(256)
void vq_argmin(const float* __restrict__ x, const float* __restrict__ dot,
               const float* __restrict__ c2, int* __restrict__ idx_i,
               float* __restrict__ idx_f)
{
    __shared__ float red[4];
    __shared__ float redv[4];
    __shared__ int   redi[4];
    const int r = blockIdx.x, tid = threadIdx.x;
    const float4 v = *(const float4*)(x + (long)r * D_ + (tid << 2));
    float s = v.x * v.x + v.y * v.y + v.z * v.z + v.w * v.w;
#pragma unroll
    for (int off = 32; off >= 1; off >>= 1) s += __shfl_xor(s, off);
    const int wid = tid >> 6, lane = tid & 63;
    if (lane == 0) red[wid] = s;
    __syncthreads();
    const float a = red[0] + red[1] + red[2] + red[3];

    float best = 3.4e38f; int bidx = 0;
    const float* dr = dot + (long)r * KC_;
    for (int j = tid; j < KC_; j += 256) {
        const float d = (a - 2.f * dr[j]) + c2[j];
        if (d < best) { best = d; bidx = j; }
    }
#pragma unroll
    for (int off = 32; off >= 1; off >>= 1) {
        const float ob = __shfl_xor(best, off);
        const int   oi = __shfl_xor(bidx, off);
        if (ob < best || (ob == best && oi < bidx)) { best = ob; bidx = oi; }
    }
    if (lane == 0) { redv[wid] = best; redi[wid] = bidx; }
    __syncthreads();
    if (tid == 0) {
        for (int w2 = 1; w2 < 4; ++w2)
            if (redv[w2] < best || (redv[w2] == best && redi[w2] < bidx)) {
                best = redv[w2]; bidx = redi[w2];
            }
        idx_i[r] = bidx;
        idx_f[r] = (float)bidx;
    }
}

__global__ void zero_f(float* p) { p[0] = 0.f; }

__global__ __launch_bounds__(256)
void sq_diff_partial(const float* __restrict__ x, const float* __restrict__ q,
                     float* __restrict__ accum)
{
    __shared__ float red[4];
    const int r = blockIdx.x, tid = threadIdx.x;
    const long base = (long)r * D_ + (tid << 2);
    const float4 xv = *(const float4*)(x + base);
    const float4 qv = *(const float4*)(q + base);
    const float d0 = xv.x - qv.x, d1 = xv.y - qv.y, d2 = xv.z - qv.z, d3 = xv.w - qv.w;
    float s = d0 * d0 + d1 * d1 + d2 * d2 + d3 * d3;
#pragma unroll
    for (int off = 32; off >= 1; off >>= 1) s += __shfl_xor(s, off);
    const int wid = tid >> 6, lane = tid & 63;
    if (lane == 0) red[wid] = s;
    __syncthreads();
    if (tid == 0) atomicAdd(accum, red[0] + red[1] + red[2] + red[3]);
}

__global__ void loss_final(const float* __restrict__ accum, float* __restrict__ out)
{
    out[0] = 2.f * accum[0] * (1.f / (float)((long)B_ * T_ * D_));
}

// ---------------------------------------------------------------------------
extern "C" void kernel_launch(void* const* d_in, const int* in_sizes, int n_in,
                              void* d_out, int out_size, void* d_ws, size_t ws_size,
                              hipStream_t stream)
{
    const float* states      = (const float*)d_in[0];
    const int*   actions     = (const int*)  d_in[1];
    const float* enc_W       = (const float*)d_in[2];
    const float* enc_b       = (const float*)d_in[3];
    const float* act_emb     = (const float*)d_in[4];
    const float* pos_emb     = (const float*)d_in[5];
    const float* enc_qkv_w   = (const float*)d_in[6];
    const float* enc_qkv_b   = (const float*)d_in[7];
    const float* enc_out_w   = (const float*)d_in[8];
    const float* enc_out_b   = (const float*)d_in[9];
    const float* enc_ln1_g   = (const float*)d_in[10];
    const float* enc_ln1_b   = (const float*)d_in[11];
    const float* enc_ln2_g   = (const float*)d_in[12];
    const float* enc_ln2_b   = (const float*)d_in[13];
    const float* enc_ff1_w   = (const float*)d_in[14];
    const float* enc_ff1_b   = (const float*)d_in[15];
    const float* enc_ff2_w   = (const float*)d_in[16];
    const float* enc_ff2_b   = (const float*)d_in[17];
    const float* dec_sa_qkv_w= (const float*)d_in[18];
    const float* dec_sa_qkv_b= (const float*)d_in[19];
    const float* dec_sa_out_w= (const float*)d_in[20];
    const float* dec_sa_out_b= (const float*)d_in[21];
    const float* dec_ca_qkv_w= (const float*)d_in[22];
    const float* dec_ca_qkv_b= (const float*)d_in[23];
    const float* dec_ca_out_w= (const float*)d_in[24];
    const float* dec_ca_out_b= (const float*)d_in[25];
    const float* dec_ln1_g   = (const float*)d_in[26];
    const float* dec_ln1_b   = (const float*)d_in[27];
    const float* dec_ln2_g   = (const float*)d_in[28];
    const float* dec_ln2_b   = (const float*)d_in[29];
    const float* dec_ln3_g   = (const float*)d_in[30];
    const float* dec_ln3_b   = (const float*)d_in[31];
    const float* dec_ff1_w   = (const float*)d_in[32];
    const float* dec_ff1_b   = (const float*)d_in[33];
    const float* dec_ff2_w   = (const float*)d_in[34];
    const float* dec_ff2_b   = (const float*)d_in[35];
    const float* codebook    = (const float*)d_in[36];
    const float* rec_W       = (const float*)d_in[37];
    const float* rec_b       = (const float*)d_in[38];

    float* out      = (float*)d_out;
    float* pred     = out;                              // [128, 19, 512]
    float* loss_out = out + (long)B_ * (T_ - 1) * S_;
    float* idx_out  = loss_out + 1;

    const long NTOK = (long)B_ * T_;                    // 2560
    const long ROW  = NTOK * D_;

    float* w    = (float*)d_ws;
    float* se   = w;  w += ROW;
    float* xbuf = w;  w += ROW;                         // also ybuf (decoder phase)
    float* big  = w;  w += NTOK * DFF_;
    float* bufa = w;  w += ROW;
    float* bufb = w;  w += ROW;
    float* quant= w;  w += ROW;
    float* cur  = w;  w += ROW;
    float* memKV= w;  w += (long)L_ * NTOK * 2 * D_;
    float* c2   = w;  w += KC_;
    float* accum= w;  w += 1;
    int*   idx_i= (int*)w;
    float* ybuf = xbuf;                                 // phase-disjoint alias

    // bf16 weight mirrors (decoder path)
    unsigned short* wb = (unsigned short*)(idx_i + NTOK);
    unsigned short* wb_sa_qkv = wb;  wb += (long)L_ * 3 * D_ * D_;
    unsigned short* wb_sa_out = wb;  wb += (long)L_ * D_ * D_;
    unsigned short* wb_ca_qkv = wb;  wb += (long)L_ * 3 * D_ * D_;
    unsigned short* wb_ca_out = wb;  wb += (long)L_ * D_ * D_;
    unsigned short* wb_ff1    = wb;  wb += (long)L_ * DFF_ * D_;
    unsigned short* wb_ff2    = wb;  wb += (long)L_ * D_ * DFF_;
    unsigned short* wb_rec    = wb;  wb += (long)S_ * D_;
    unsigned short* wb_enc    = wb;  wb += (long)D_ * S_;
    const size_t need = (size_t)((char*)wb - (char*)d_ws);
    if (ws_size < need) return;  // fail loudly (output stays poisoned)

    auto gemm = [&](const float* A, int lda, const float* Wt, int Kd, int N, int M,
                    float* C, int ldc, const float* bias, const float* bias2, int relu) {
        dim3 g(N >> 7, M >> 7);
        gemm_nt<<<g, 256, 0, stream>>>(A, lda, Wt, Kd, C, ldc, bias, bias2, Kd, relu);
    };
    auto gemmb = [&](const float* A, int lda, const unsigned short* Wt, int Kd, int N, int M,
                     float* C, int ldc, const float* bias, const float* bias2, int relu) {
        dim3 g(N >> 7, M >> 7);
        gemm_bf16<<<g, 256, 0, stream>>>(A, lda, Wt, Kd, C, ldc, bias, bias2, Kd, relu);
    };
    auto attn = [&](const float* qp, const float* kp, const float* vp, float* op,
                    long q_bs, long q_ts, long kv_bs, long kv_ts,
                    long o_bs, long o_ts, int nq, int nk, int causal) {
        dim3 g(B_ * H_, nq);
        attn64<<<g, 64, 0, stream>>>(qp, kp, vp, op, H_, q_bs, q_ts, kv_bs, kv_ts,
                                     o_bs, o_ts, nk, causal, 0.125f);
    };
    auto conv = [&](const float* s, unsigned short* d, long n) {
        const long n4 = n >> 2;
        convert_f2bf<<<(int)((n4 + 255) >> 8), 256, 0, stream>>>(s, d, n4);
    };

    // ---- weight conversions (decoder path only) ----
    conv(dec_sa_qkv_w, wb_sa_qkv, (long)L_ * 3 * D_ * D_);
    conv(dec_sa_out_w, wb_sa_out, (long)L_ * D_ * D_);
    conv(dec_ca_qkv_w, wb_ca_qkv, (long)L_ * 3 * D_ * D_);
    conv(dec_ca_out_w, wb_ca_out, (long)L_ * D_ * D_);
    conv(dec_ff1_w,    wb_ff1,    (long)L_ * DFF_ * D_);
    conv(dec_ff2_w,    wb_ff2,    (long)L_ * D_ * DFF_);
    conv(rec_W,        wb_rec,    (long)S_ * D_);
    conv(enc_W,        wb_enc,    (long)D_ * S_);

    // ======================= Encoder (fp32 — idx exactness) =======================
    gemm(states, S_, enc_W, S_, D_, (int)NTOK, se, D_, enc_b, nullptr, 0);
    embed_add<<<(int)NTOK, 256, 0, stream>>>(se, actions, act_emb, pos_emb, xbuf);

    for (int i = 0; i < L_; ++i) {
        gemm(xbuf, D_, enc_qkv_w + (long)i * 3 * D_ * D_, D_, 3 * D_, (int)NTOK,
             big, 3 * D_, enc_qkv_b + (long)i * 3 * D_, nullptr, 0);
        attn(big, big + D_, big + 2 * D_, bufa,
             (long)T_ * 3 * D_, 3 * D_, (long)T_ * 3 * D_, 3 * D_,
             (long)T_ * D_, D_, T_, T_, 0);
        gemm(bufa, D_, enc_out_w + (long)i * D_ * D_, D_, D_, (int)NTOK,
             bufb, D_, enc_out_b + i * D_, nullptr, 0);
        ln_res<<<(int)NTOK, 256, 0, stream>>>(xbuf, bufb, enc_ln1_g + i * D_, enc_ln1_b + i * D_, xbuf);
        gemm(xbuf, D_, enc_ff1_w + (long)i * DFF_ * D_, D_, DFF_, (int)NTOK,
             big, DFF_, enc_ff1_b + i * DFF_, nullptr, 1);
        gemm(big, DFF_, enc_ff2_w + (long)i * D_ * DFF_, DFF_, D_, (int)NTOK,
             bufb, D_, enc_ff2_b + i * D_, nullptr, 0);
        ln_res<<<(int)NTOK, 256, 0, stream>>>(xbuf, bufb, enc_ln2_g + i * D_, enc_ln2_b + i * D_, xbuf);
    }

    // ======================= VQ (fp32, numpy order) =======================
    row_sumsq<<<KC_, 256, 0, stream>>>(codebook, c2);
    gemm(xbuf, D_, codebook, D_, KC_, (int)NTOK, big, KC_, nullptr, nullptr, 0);
    vq_argmin<<<(int)NTOK, 256, 0, stream>>>(xbuf, big, c2, idx_i, idx_out);
    quant_build<<<(int)NTOK, 256, 0, stream>>>(idx_i, codebook, quant);
    zero_f<<<1, 1, 0, stream>>>(accum);
    sq_diff_partial<<<(int)NTOK, 256, 0, stream>>>(xbuf, quant, accum);
    loss_final<<<1, 1, 0, stream>>>(accum, loss_out);

    // ============ Decoder: precompute cross-attn K/V (bf16 MFMA) ============
    for (int i = 0; i < L_; ++i) {
        const unsigned short* wkv = wb_ca_qkv + (long)i * 3 * D_ * D_ + (long)D_ * D_;
        const float* bkv = dec_ca_qkv_b + (long)i * 3 * D_ + D_;
        gemmb(quant, D_, wkv, D_, 2 * D_, (int)NTOK,
              memKV + (long)i * NTOK * 2 * D_, 2 * D_, bkv, nullptr, 0);
    }
    cur0_init<<<B_, 256, 0, stream>>>(se, pos_emb, cur);

    // ============ Decoder: 19 autoregressive steps (bf16 MFMA GEMMs) ============
    for (int t = 0; t < T_ - 1; ++t) {
        const int P = t + 1;
        const int M = B_ * P;
        assemble_y<<<M, 256, 0, stream>>>(cur, ybuf, P);

        for (int i = 0; i < L_; ++i) {
            // --- causal self-attention ---
            gemmb(ybuf, D_, wb_sa_qkv + (long)i * 3 * D_ * D_, D_, 3 * D_, M,
                  big, 3 * D_, dec_sa_qkv_b + (long)i * 3 * D_, nullptr, 0);
            attn(big, big + D_, big + 2 * D_, bufa,
                 (long)P * 3 * D_, 3 * D_, (long)P * 3 * D_, 3 * D_,
                 (long)P * D_, D_, P, P, 1);
            gemmb(bufa, D_, wb_sa_out + (long)i * D_ * D_, D_, D_, M,
                  bufb, D_, dec_sa_out_b + i * D_, nullptr, 0);
            ln_res<<<M, 256, 0, stream>>>(ybuf, bufb, dec_ln1_g + i * D_, dec_ln1_b + i * D_, ybuf);

            // --- cross-attention (memory fixed -> precomputed memKV) ---
            gemmb(ybuf, D_, wb_ca_qkv + (long)i * 3 * D_ * D_, D_, D_, M,
                  bufa, D_, dec_ca_qkv_b + (long)i * 3 * D_, nullptr, 0);
            const float* mkv = memKV + (long)i * NTOK * 2 * D_;
            attn(bufa, mkv, mkv + D_, big,
                 (long)P * D_, D_, (long)T_ * 2 * D_, 2 * D_,
                 (long)P * D_, D_, P, P, 0);
            gemmb(big, D_, wb_ca_out + (long)i * D_ * D_, D_, D_, M,
                  bufb, D_, dec_ca_out_b + i * D_, nullptr, 0);
            ln_res<<<M, 256, 0, stream>>>(ybuf, bufb, dec_ln2_g + i * D_, dec_ln2_b + i * D_, ybuf);

            // --- FFN ---
            gemmb(ybuf, D_, wb_ff1 + (long)i * DFF_ * D_, D_, DFF_, M,
                  big, DFF_, dec_ff1_b + i * DFF_, nullptr, 1);
            gemmb(big, DFF_, wb_ff2 + (long)i * D_ * DFF_, DFF_, D_, M,
                  bufb, D_, dec_ff2_b + i * D_, nullptr, 0);
            ln_res<<<M, 256, 0, stream>>>(ybuf, bufb, dec_ln3_g + i * D_, dec_ln3_b + i * D_, ybuf);
        }

        // preds[t] = y[:, -1] @ rec_W^T + rec_b  -> pred[:, t, :]
        gemmb(ybuf + (long)(P - 1) * D_, P * D_, wb_rec, D_, S_, B_,
              pred + (long)t * S_, (T_ - 1) * S_, rec_b, nullptr, 0);

        // dec_in[:, t+1] = preds[t] @ enc_W^T + enc_b + pos_emb[t+1]
        if (t < T_ - 2)
            gemmb(pred + (long)t * S_, (T_ - 1) * S_, wb_enc, S_, D_, B_,
                  cur + (long)(t + 1) * D_, T_ * D_, enc_b, pos_emb + (long)(t + 1) * D_, 0);
    }
}

// Round 3
// 41055.133 us; speedup vs baseline: 2.5404x; 1.3025x over previous
//
#include <hip/hip_runtime.h>
#include <math.h>

// Problem constants
#define B_   128
#define T_   20
#define S_   512
#define D_   1024
#define H_   16
#define L_   4
#define KC_  2048   // codebook size
#define DFF_ 4096

typedef __attribute__((ext_vector_type(8))) short bf16x8;   // 8 bf16 (4 VGPRs)
typedef __attribute__((ext_vector_type(4))) float f32x4;

__device__ __forceinline__ unsigned short f2bf_rne(float f) {
    unsigned u = __float_as_uint(f);
    u += 0x7fffu + ((u >> 16) & 1u);
    return (unsigned short)(u >> 16);
}
__device__ __forceinline__ unsigned pack2(float a, float b) {
    return (unsigned)f2bf_rne(a) | ((unsigned)f2bf_rne(b) << 16);
}

// ---------------------------------------------------------------------------
// fp32 GEMM (encoder + VQ path — bit-stable vs round 1):
// C[M,N] = A[M,K] * W[N,K]^T (+bias)(+bias2)(+relu); M%128==0, N%128==0, K%16==0
// ---------------------------------------------------------------------------
__global__ __launch_bounds__(256, 2)
void gemm_nt(const float* __restrict__ A, int lda,
             const float* __restrict__ W, int ldb,
             float* __restrict__ C, int ldc,
             const float* __restrict__ bias,
             const float* __restrict__ bias2,
             int Kd, int relu)
{
    __shared__ float As[16][132];
    __shared__ float Bs[16][132];
    const int tid = threadIdx.x;
    const int m0 = blockIdx.y << 7;
    const int n0 = blockIdx.x << 7;
    const int tx = tid & 15;
    const int ty = tid >> 4;

    float acc[2][2][4][4];
#pragma unroll
    for (int a = 0; a < 2; ++a)
#pragma unroll
        for (int b = 0; b < 2; ++b)
#pragma unroll
            for (int i = 0; i < 4; ++i)
#pragma unroll
                for (int j = 0; j < 4; ++j) acc[a][b][i][j] = 0.f;

    const int lrow = tid >> 2;
    const int lkk  = (tid & 3) << 2;
    const float* Ap0 = A + (long)(m0 + lrow)      * lda + lkk;
    const float* Ap1 = A + (long)(m0 + lrow + 64) * lda + lkk;
    const float* Bp0 = W + (long)(n0 + lrow)      * ldb + lkk;
    const float* Bp1 = W + (long)(n0 + lrow + 64) * ldb + lkk;

    for (int k0 = 0; k0 < Kd; k0 += 16) {
        const float4 a0 = *(const float4*)(Ap0 + k0);
        const float4 a1 = *(const float4*)(Ap1 + k0);
        const float4 b0 = *(const float4*)(Bp0 + k0);
        const float4 b1 = *(const float4*)(Bp1 + k0);
        __syncthreads();
        As[lkk + 0][lrow] = a0.x; As[lkk + 1][lrow] = a0.y;
        As[lkk + 2][lrow] = a0.z; As[lkk + 3][lrow] = a0.w;
        As[lkk + 0][lrow + 64] = a1.x; As[lkk + 1][lrow + 64] = a1.y;
        As[lkk + 2][lrow + 64] = a1.z; As[lkk + 3][lrow + 64] = a1.w;
        Bs[lkk + 0][lrow] = b0.x; Bs[lkk + 1][lrow] = b0.y;
        Bs[lkk + 2][lrow] = b0.z; Bs[lkk + 3][lrow] = b0.w;
        Bs[lkk + 0][lrow + 64] = b1.x; Bs[lkk + 1][lrow + 64] = b1.y;
        Bs[lkk + 2][lrow + 64] = b1.z; Bs[lkk + 3][lrow + 64] = b1.w;
        __syncthreads();
#pragma unroll
        for (int kk = 0; kk < 16; ++kk) {
            const float4 aLo = *(const float4*)&As[kk][ty << 2];
            const float4 aHi = *(const float4*)&As[kk][(ty << 2) + 64];
            const float4 bLo = *(const float4*)&Bs[kk][tx << 2];
            const float4 bHi = *(const float4*)&Bs[kk][(tx << 2) + 64];
            const float am[2][4] = {{aLo.x, aLo.y, aLo.z, aLo.w},
                                    {aHi.x, aHi.y, aHi.z, aHi.w}};
            const float bn[2][4] = {{bLo.x, bLo.y, bLo.z, bLo.w},
                                    {bHi.x, bHi.y, bHi.z, bHi.w}};
#pragma unroll
            for (int mi = 0; mi < 2; ++mi)
#pragma unroll
                for (int i = 0; i < 4; ++i) {
                    const float av = am[mi][i];
#pragma unroll
                    for (int ni = 0; ni < 2; ++ni) {
                        acc[mi][ni][i][0] += av * bn[ni][0];
                        acc[mi][ni][i][1] += av * bn[ni][1];
                        acc[mi][ni][i][2] += av * bn[ni][2];
                        acc[mi][ni][i][3] += av * bn[ni][3];
                    }
                }
        }
    }

#pragma unroll
    for (int mi = 0; mi < 2; ++mi)
#pragma unroll
        for (int i = 0; i < 4; ++i) {
            const int m = m0 + (mi << 6) + (ty << 2) + i;
            float* crow = C + (long)m * ldc + n0;
#pragma unroll
            for (int ni = 0; ni < 2; ++ni) {
                const int n = (ni << 6) + (tx << 2);
                float4 v = make_float4(acc[mi][ni][i][0], acc[mi][ni][i][1],
                                       acc[mi][ni][i][2], acc[mi][ni][i][3]);
                if (bias) {
                    v.x += bias[n0 + n];     v.y += bias[n0 + n + 1];
                    v.z += bias[n0 + n + 2]; v.w += bias[n0 + n + 3];
                }
                if (bias2) {
                    v.x += bias2[n0 + n];     v.y += bias2[n0 + n + 1];
                    v.z += bias2[n0 + n + 2]; v.w += bias2[n0 + n + 3];
                }
                if (relu) {
                    v.x = fmaxf(v.x, 0.f); v.y = fmaxf(v.y, 0.f);
                    v.z = fmaxf(v.z, 0.f); v.w = fmaxf(v.w, 0.f);
                }
                *(float4*)(crow + n) = v;
            }
        }
}

// ---------------------------------------------------------------------------
// bf16 MFMA GEMM v2 (decoder): C[M,N] = A_f32[M,K] * Wbf16[N,K]^T
// 64x128 tile, BK=64, 4 waves (each 32x64 = 2x4 of 16x16x32 MFMA), adaptive
// split-K: grid.z slices of ksl K-elems, fp32 atomicAdd epilogue, slice 0
// carries bias; C must be zeroed when splitk>1. relu only when splitk==1.
// arelu applies max(0,.) to A during staging. M%64==0, N%128==0, ksl%64==0.
// Fragment layouts per learn_hip m89/m91 (verified on gfx950, round 2 passed).
// ---------------------------------------------------------------------------
#define LDSP 72

__global__ __launch_bounds__(256, 2)
void gemm_bf16(const float* __restrict__ A, int lda,
               const unsigned short* __restrict__ W, int ldb,
               float* __restrict__ C, int ldc,
               const float* __restrict__ bias,
               const float* __restrict__ bias2,
               int ksl, int splitk, int relu, int arelu)
{
    __shared__ unsigned short As[64 * LDSP];
    __shared__ unsigned short Bs[128 * LDSP];
    const int tid = threadIdx.x;
    const int m0 = blockIdx.y << 6;
    const int n0 = blockIdx.x << 7;
    const int kbeg = blockIdx.z * ksl;
    const int wave = tid >> 6;
    const int lane = tid & 63;
    const int wm = (wave & 1) << 5;     // 0 / 32
    const int wn = (wave >> 1) << 6;    // 0 / 64
    const int lrow = lane & 15;
    const int q = lane >> 4;

    const int srowA = tid >> 2;          // 0..63
    const int scolA = (tid & 3) << 4;    // 0,16,32,48
    const int srowB = tid >> 1;          // 0..127
    const int scolB = (tid & 1) << 5;    // 0,32

    const float*          Ap = A + (long)(m0 + srowA) * lda + scolA + kbeg;
    const unsigned short* Bp = W + (long)(n0 + srowB) * ldb + scolB + kbeg;
    unsigned short* AsW = &As[srowA * LDSP + scolA];
    unsigned short* BsW = &Bs[srowB * LDSP + scolB];

    f32x4 acc[2][4];
#pragma unroll
    for (int i = 0; i < 2; ++i)
#pragma unroll
        for (int j = 0; j < 4; ++j) acc[i][j] = (f32x4){0.f, 0.f, 0.f, 0.f};

    for (int k0 = 0; k0 < ksl; k0 += 64) {
        float4 a4[4];
#pragma unroll
        for (int i = 0; i < 4; ++i) a4[i] = *(const float4*)(Ap + k0 + i * 4);
        if (arelu) {
#pragma unroll
            for (int i = 0; i < 4; ++i) {
                a4[i].x = fmaxf(a4[i].x, 0.f); a4[i].y = fmaxf(a4[i].y, 0.f);
                a4[i].z = fmaxf(a4[i].z, 0.f); a4[i].w = fmaxf(a4[i].w, 0.f);
            }
        }
        uint4 bv[4];
#pragma unroll
        for (int i = 0; i < 4; ++i) bv[i] = *(const uint4*)(Bp + k0 + i * 8);

        __syncthreads();
        {
            uint4 w0, w1;
            w0.x = pack2(a4[0].x, a4[0].y); w0.y = pack2(a4[0].z, a4[0].w);
            w0.z = pack2(a4[1].x, a4[1].y); w0.w = pack2(a4[1].z, a4[1].w);
            w1.x = pack2(a4[2].x, a4[2].y); w1.y = pack2(a4[2].z, a4[2].w);
            w1.z = pack2(a4[3].x, a4[3].y); w1.w = pack2(a4[3].z, a4[3].w);
            ((uint4*)AsW)[0] = w0;
            ((uint4*)AsW)[1] = w1;
        }
#pragma unroll
        for (int i = 0; i < 4; ++i) ((uint4*)BsW)[i] = bv[i];
        __syncthreads();

#pragma unroll
        for (int kk = 0; kk < 2; ++kk) {
            bf16x8 af[2], bfr[4];
#pragma unroll
            for (int mi = 0; mi < 2; ++mi)
                af[mi] = *(const bf16x8*)&As[(wm + mi * 16 + lrow) * LDSP + kk * 32 + q * 8];
#pragma unroll
            for (int ni = 0; ni < 4; ++ni)
                bfr[ni] = *(const bf16x8*)&Bs[(wn + ni * 16 + lrow) * LDSP + kk * 32 + q * 8];
#pragma unroll
            for (int mi = 0; mi < 2; ++mi)
#pragma unroll
                for (int ni = 0; ni < 4; ++ni)
                    acc[mi][ni] = __builtin_amdgcn_mfma_f32_16x16x32_bf16(
                        af[mi], bfr[ni], acc[mi][ni], 0, 0, 0);
        }
    }

    // C/D layout: col = lane&15, row = (lane>>4)*4 + reg   [m89/m91]
    const int addb = (blockIdx.z == 0);
#pragma unroll
    for (int mi = 0; mi < 2; ++mi) {
#pragma unroll
        for (int r = 0; r < 4; ++r) {
            const int m = m0 + wm + mi * 16 + q * 4 + r;
            float* crow = C + (long)m * ldc + n0 + wn;
#pragma unroll
            for (int ni = 0; ni < 4; ++ni) {
                const int n = ni * 16 + lrow;
                float v = acc[mi][ni][r];
                if (splitk == 1) {
                    if (bias)  v += bias[n0 + wn + n];
                    if (bias2) v += bias2[n0 + wn + n];
                    if (relu)  v = fmaxf(v, 0.f);
                    crow[n] = v;
                } else {
                    if (addb) {
                        if (bias)  v += bias[n0 + wn + n];
                        if (bias2) v += bias2[n0 + wn + n];
                    }
                    atomicAdd(crow + n, v);
                }
            }
        }
    }
}

// zero a strided MxN fp32 region (ldc != N); one block per row, float4/thread
__global__ void zero2d(float* __restrict__ C, int ldc)
{
    *(float4*)(C + (long)blockIdx.x * ldc + (threadIdx.x << 2)) =
        make_float4(0.f, 0.f, 0.f, 0.f);
}

// fp32 -> bf16 (RNE) bulk convert; n4 = n/4 float4 groups
__global__ __launch_bounds__(256)
void convert_f2bf(const float* __restrict__ src, unsigned short* __restrict__ dst, long n4)
{
    const long i = (long)blockIdx.x * 256 + threadIdx.x;
    if (i < n4) {
        const float4 v = ((const float4*)src)[i];
        uint2 o;
        o.x = pack2(v.x, v.y);
        o.y = pack2(v.z, v.w);
        ((uint2*)dst)[i] = o;
    }
}

// ---------------------------------------------------------------------------
// Attention for hd=64: one wave per (b, h, query-pos). nkeys <= 20.
// ---------------------------------------------------------------------------
__global__ __launch_bounds__(64)
void attn64(const float* __restrict__ qp, const float* __restrict__ kp,
            const float* __restrict__ vp, float* __restrict__ op,
            int H, long q_bs, long q_ts, long kv_bs, long kv_ts,
            long o_bs, long o_ts, int nk, int causal, float scale)
{
    const int b  = blockIdx.x / H;
    const int h  = blockIdx.x % H;
    const int qj = blockIdx.y;
    const int tid = threadIdx.x;
    __shared__ float sc[32];

    const float qv = qp[(long)b * q_bs + (long)qj * q_ts + h * 64 + tid];
    const int nkeys = causal ? (qj + 1) : nk;
    const long kbase = (long)b * kv_bs + h * 64 + tid;

    for (int j = 0; j < nkeys; ++j) {
        float p = qv * kp[kbase + (long)j * kv_ts];
#pragma unroll
        for (int off = 32; off >= 1; off >>= 1) p += __shfl_xor(p, off);
        if (tid == 0) sc[j] = p * scale;
    }
    __syncthreads();

    const float sval = (tid < nkeys) ? sc[tid] : -INFINITY;
    float mx = sval;
#pragma unroll
    for (int off = 32; off >= 1; off >>= 1) mx = fmaxf(mx, __shfl_xor(mx, off));
    const float e = (tid < nkeys) ? expf(sval - mx) : 0.f;
    float ssum = e;
#pragma unroll
    for (int off = 32; off >= 1; off >>= 1) ssum += __shfl_xor(ssum, off);
    if (tid < nkeys) sc[tid] = e / ssum;
    __syncthreads();

    float acc = 0.f;
    for (int j = 0; j < nkeys; ++j) acc += sc[j] * vp[kbase + (long)j * kv_ts];
    op[(long)b * o_bs + (long)qj * o_ts + h * 64 + tid] = acc;
}

// ---------------------------------------------------------------------------
// LayerNorm with residual
// ---------------------------------------------------------------------------
__global__ __launch_bounds__(256)
void ln_res(const float* __restrict__ x, const float* __restrict__ hh,
            const float* __restrict__ g, const float* __restrict__ bta,
            float* __restrict__ out)
{
    __shared__ float red[4];
    const int r = blockIdx.x, tid = threadIdx.x;
    const long base = (long)r * D_ + (tid << 2);
    const float4 xv = *(const float4*)(x + base);
    const float4 hv = *(const float4*)(hh + base);
    const float v0 = xv.x + hv.x, v1 = xv.y + hv.y, v2 = xv.z + hv.z, v3 = xv.w + hv.w;

    float s = v0 + v1 + v2 + v3;
#pragma unroll
    for (int off = 32; off >= 1; off >>= 1) s += __shfl_xor(s, off);
    const int wid = tid >> 6, lane = tid & 63;
    if (lane == 0) red[wid] = s;
    __syncthreads();
    const float mean = (red[0] + red[1] + red[2] + red[3]) * (1.f / D_);
    __syncthreads();

    const float d0 = v0 - mean, d1 = v1 - mean, d2 = v2 - mean, d3 = v3 - mean;
    float s2 = d0 * d0 + d1 * d1 + d2 * d2 + d3 * d3;
#pragma unroll
    for (int off = 32; off >= 1; off >>= 1) s2 += __shfl_xor(s2, off);
    if (lane == 0) red[wid] = s2;
    __syncthreads();
    const float var = (red[0] + red[1] + red[2] + red[3]) * (1.f / D_);
    const float rs = 1.f / sqrtf(var + 1e-5f);

    const float4 gv = *(const float4*)(g + (tid << 2));
    const float4 bv = *(const float4*)(bta + (tid << 2));
    float4 o;
    o.x = d0 * rs * gv.x + bv.x; o.y = d1 * rs * gv.y + bv.y;
    o.z = d2 * rs * gv.z + bv.z; o.w = d3 * rs * gv.w + bv.w;
    *(float4*)(out + base) = o;
}

__global__ void embed_add(const float* __restrict__ se, const int* __restrict__ actions,
                          const float* __restrict__ act_emb, const float* __restrict__ pos,
                          float* __restrict__ x)
{
    const int r = blockIdx.x, c = threadIdx.x << 2;
    const int t = r % T_;
    const int a = actions[r];
    const float4 sv = *(const float4*)(se + (long)r * D_ + c);
    const float4 av = *(const float4*)(act_emb + (long)a * D_ + c);
    const float4 pv = *(const float4*)(pos + (long)t * D_ + c);
    float4 o;
    o.x = sv.x + av.x + pv.x; o.y = sv.y + av.y + pv.y;
    o.z = sv.z + av.z + pv.z; o.w = sv.w + av.w + pv.w;
    *(float4*)(x + (long)r * D_ + c) = o;
}

__global__ void cur0_init(const float* __restrict__ se, const float* __restrict__ pos,
                          float* __restrict__ cur)
{
    const int b = blockIdx.x, c = threadIdx.x << 2;
    const long base = (long)b * T_ * D_ + c;
    const float4 sv = *(const float4*)(se + base);
    const float4 pv = *(const float4*)(pos + c);
    float4 o; o.x = sv.x + pv.x; o.y = sv.y + pv.y; o.z = sv.z + pv.z; o.w = sv.w + pv.w;
    *(float4*)(cur + base) = o;
}

__global__ void assemble_y(const float* __restrict__ cur, float* __restrict__ y, int P)
{
    const int r = blockIdx.x;
    const int b = r / P, j = r - b * P;
    const int c = threadIdx.x << 2;
    *(float4*)(y + (long)r * D_ + c) =
        *(const float4*)(cur + ((long)b * T_ + j) * D_ + c);
}

__global__ void quant_build(const int* __restrict__ idx, const float* __restrict__ cb,
                            float* __restrict__ quant)
{
    const int r = blockIdx.x, c = threadIdx.x << 2;
    const int code = idx[r];
    *(float4*)(quant + (long)r * D_ + c) = *(const float4*)(cb + (long)code * D_ + c);
}

__global__ __launch_bounds__(256)
void row_sumsq(const float* __restrict__ A, float* __restrict__ out)
{
    __shared__ float red[4];
    const int r = blockIdx.x, tid = threadIdx.x;
    const float4 v = *(const float4*)(A + (long)r * D_ + (tid << 2));
    float s = v.x * v.x + v.y * v.y + v.z * v.z + v.w * v.w;
#pragma unroll
    for (int off = 32; off >= 1; off >>= 1) s += __shfl_xor(s, off);
    const int wid = tid >> 6, lane = tid & 63;
    if (lane == 0) red[wid] = s;
    __syncthreads();
    if (tid == 0) out[r] = red[0] + red[1] + red[2] + red[3];
}

__global__ __launch_bounds__(256)
void vq_argmin(const float* __restrict__ x, const float* __restrict__ dot,
               const float* __restrict__ c2, int* __restrict__ idx_i,
               float* __restrict__ idx_f)
{
    __shared__ float red[4];
    __shared__ float redv[4];
    __shared__ int   redi[4];
    const int r = blockIdx.x, tid = threadIdx.x;
    const float4 v = *(const float4*)(x + (long)r * D_ + (tid << 2));
    float s = v.x * v.x + v.y * v.y + v.z * v.z + v.w * v.w;
#pragma unroll
    for (int off = 32; off >= 1; off >>= 1) s += __shfl_xor(s, off);
    const int wid = tid >> 6, lane = tid & 63;
    if (lane == 0) red[wid] = s;
    __syncthreads();
    const float a = red[0] + red[1] + red[2] + red[3];

    float best = 3.4e38f; int bidx = 0;
    const float* dr = dot + (long)r * KC_;
    for (int j = tid; j < KC_; j += 256) {
        const float d = (a - 2.f * dr[j]) + c2[j];
        if (d < best) { best = d; bidx = j; }
    }
#pragma unroll
    for (int off = 32; off >= 1; off >>= 1) {
        const float ob = __shfl_xor(best, off);
        const int   oi = __shfl_xor(bidx, off);
        if (ob < best || (ob == best && oi < bidx)) { best = ob; bidx = oi; }
    }
    if (lane == 0) { redv[wid] = best; redi[wid] = bidx; }
    __syncthreads();
    if (tid == 0) {
        for (int w2 = 1; w2 < 4; ++w2)
            if (redv[w2] < best || (redv[w2] == best && redi[w2] < bidx)) {
                best = redv[w2]; bidx = redi[w2];
            }
        idx_i[r] = bidx;
        idx_f[r] = (float)bidx;
    }
}

__global__ void zero_f(float* p) { p[0] = 0.f; }

__global__ __launch_bounds__(256)
void sq_diff_partial(const float* __restrict__ x, const float* __restrict__ q,
                     float* __restrict__ accum)
{
    __shared__ float red[4];
    const int r = blockIdx.x, tid = threadIdx.x;
    const long base = (long)r * D_ + (tid << 2);
    const float4 xv = *(const float4*)(x + base);
    const float4 qv = *(const float4*)(q + base);
    const float d0 = xv.x - qv.x, d1 = xv.y - qv.y, d2 = xv.z - qv.z, d3 = xv.w - qv.w;
    float s = d0 * d0 + d1 * d1 + d2 * d2 + d3 * d3;
#pragma unroll
    for (int off = 32; off >= 1; off >>= 1) s += __shfl_xor(s, off);
    const int wid = tid >> 6, lane = tid & 63;
    if (lane == 0) red[wid] = s;
    __syncthreads();
    if (tid == 0) atomicAdd(accum, red[0] + red[1] + red[2] + red[3]);
}

__global__ void loss_final(const float* __restrict__ accum, float* __restrict__ out)
{
    out[0] = 2.f * accum[0] * (1.f / (float)((long)B_ * T_ * D_));
}

// ---------------------------------------------------------------------------
extern "C" void kernel_launch(void* const* d_in, const int* in_sizes, int n_in,
                              void* d_out, int out_size, void* d_ws, size_t ws_size,
                              hipStream_t stream)
{
    const float* states      = (const float*)d_in[0];
    const int*   actions     = (const int*)  d_in[1];
    const float* enc_W       = (const float*)d_in[2];
    const float* enc_b       = (const float*)d_in[3];
    const float* act_emb     = (const float*)d_in[4];
    const float* pos_emb     = (const float*)d_in[5];
    const float* enc_qkv_w   = (const float*)d_in[6];
    const float* enc_qkv_b   = (const float*)d_in[7];
    const float* enc_out_w   = (const float*)d_in[8];
    const float* enc_out_b   = (const float*)d_in[9];
    const float* enc_ln1_g   = (const float*)d_in[10];
    const float* enc_ln1_b   = (const float*)d_in[11];
    const float* enc_ln2_g   = (const float*)d_in[12];
    const float* enc_ln2_b   = (const float*)d_in[13];
    const float* enc_ff1_w   = (const float*)d_in[14];
    const float* enc_ff1_b   = (const float*)d_in[15];
    const float* enc_ff2_w   = (const float*)d_in[16];
    const float* enc_ff2_b   = (const float*)d_in[17];
    const float* dec_sa_qkv_w= (const float*)d_in[18];
    const float* dec_sa_qkv_b= (const float*)d_in[19];
    const float* dec_sa_out_w= (const float*)d_in[20];
    const float* dec_sa_out_b= (const float*)d_in[21];
    const float* dec_ca_qkv_w= (const float*)d_in[22];
    const float* dec_ca_qkv_b= (const float*)d_in[23];
    const float* dec_ca_out_w= (const float*)d_in[24];
    const float* dec_ca_out_b= (const float*)d_in[25];
    const float* dec_ln1_g   = (const float*)d_in[26];
    const float* dec_ln1_b   = (const float*)d_in[27];
    const float* dec_ln2_g   = (const float*)d_in[28];
    const float* dec_ln2_b   = (const float*)d_in[29];
    const float* dec_ln3_g   = (const float*)d_in[30];
    const float* dec_ln3_b   = (const float*)d_in[31];
    const float* dec_ff1_w   = (const float*)d_in[32];
    const float* dec_ff1_b   = (const float*)d_in[33];
    const float* dec_ff2_w   = (const float*)d_in[34];
    const float* dec_ff2_b   = (const float*)d_in[35];
    const float* codebook    = (const float*)d_in[36];
    const float* rec_W       = (const float*)d_in[37];
    const float* rec_b       = (const float*)d_in[38];

    float* out      = (float*)d_out;
    float* pred     = out;                              // [128, 19, 512]
    float* loss_out = out + (long)B_ * (T_ - 1) * S_;
    float* idx_out  = loss_out + 1;

    const long NTOK = (long)B_ * T_;                    // 2560
    const long ROW  = NTOK * D_;

    float* w    = (float*)d_ws;
    float* se   = w;  w += ROW;
    float* xbuf = w;  w += ROW;                         // also ybuf (decoder phase)
    float* big  = w;  w += NTOK * DFF_;
    float* bufa = w;  w += ROW;
    float* bufb = w;  w += ROW;
    float* quant= w;  w += ROW;
    float* cur  = w;  w += ROW;
    float* memKV= w;  w += (long)L_ * NTOK * 2 * D_;
    float* c2   = w;  w += KC_;
    float* accum= w;  w += 1;
    int*   idx_i= (int*)w;
    float* ybuf = xbuf;                                 // phase-disjoint alias

    // bf16 weight mirrors (decoder path)
    unsigned short* wb = (unsigned short*)(idx_i + NTOK);
    unsigned short* wb_sa_qkv = wb;  wb += (long)L_ * 3 * D_ * D_;
    unsigned short* wb_sa_out = wb;  wb += (long)L_ * D_ * D_;
    unsigned short* wb_ca_qkv = wb;  wb += (long)L_ * 3 * D_ * D_;
    unsigned short* wb_ca_out = wb;  wb += (long)L_ * D_ * D_;
    unsigned short* wb_ff1    = wb;  wb += (long)L_ * DFF_ * D_;
    unsigned short* wb_ff2    = wb;  wb += (long)L_ * D_ * DFF_;
    unsigned short* wb_rec    = wb;  wb += (long)S_ * D_;
    unsigned short* wb_enc    = wb;  wb += (long)D_ * S_;
    const size_t need = (size_t)((char*)wb - (char*)d_ws);
    if (ws_size < need) return;  // fail loudly (output stays poisoned)

    auto gemm = [&](const float* A, int lda, const float* Wt, int Kd, int N, int M,
                    float* C, int ldc, const float* bias, const float* bias2, int relu) {
        dim3 g(N >> 7, M >> 7);
        gemm_nt<<<g, 256, 0, stream>>>(A, lda, Wt, Kd, C, ldc, bias, bias2, Kd, relu);
    };
    // bf16 gemm, adaptive split-K. strided: 0 = contiguous C (memset ok),
    // 1 = strided C (zero2d). arelu: relu on A-read.
    auto gemmb = [&](const float* A, int lda, const unsigned short* Wt, int Kd, int N, int M,
                     float* C, int ldc, const float* bias, const float* bias2,
                     int relu, int arelu, int strided) {
        const long base = (long)(M >> 6) * (N >> 7);
        int sk = 1;
        while (sk < 16) {
            const int nx = sk << 1;
            if (Kd % (64 * nx)) break;
            if (base * sk >= 256) break;
            sk = nx;
        }
        if (sk > 1) {
            if (strided) zero2d<<<M, N >> 2, 0, stream>>>(C, ldc);
            else hipMemsetAsync(C, 0, (size_t)M * N * sizeof(float), stream);
        }
        dim3 g(N >> 7, M >> 6, sk);
        gemm_bf16<<<g, 256, 0, stream>>>(A, lda, Wt, Kd, C, ldc, bias, bias2,
                                         Kd / sk, sk, relu, arelu);
    };
    auto attn = [&](const float* qp, const float* kp, const float* vp, float* op,
                    long q_bs, long q_ts, long kv_bs, long kv_ts,
                    long o_bs, long o_ts, int nq, int nk, int causal) {
        dim3 g(B_ * H_, nq);
        attn64<<<g, 64, 0, stream>>>(qp, kp, vp, op, H_, q_bs, q_ts, kv_bs, kv_ts,
                                     o_bs, o_ts, nk, causal, 0.125f);
    };
    auto conv = [&](const float* s, unsigned short* d, long n) {
        const long n4 = n >> 2;
        convert_f2bf<<<(int)((n4 + 255) >> 8), 256, 0, stream>>>(s, d, n4);
    };

    // ---- weight conversions (decoder path only) ----
    conv(dec_sa_qkv_w, wb_sa_qkv, (long)L_ * 3 * D_ * D_);
    conv(dec_sa_out_w, wb_sa_out, (long)L_ * D_ * D_);
    conv(dec_ca_qkv_w, wb_ca_qkv, (long)L_ * 3 * D_ * D_);
    conv(dec_ca_out_w, wb_ca_out, (long)L_ * D_ * D_);
    conv(dec_ff1_w,    wb_ff1,    (long)L_ * DFF_ * D_);
    conv(dec_ff2_w,    wb_ff2,    (long)L_ * D_ * DFF_);
    conv(rec_W,        wb_rec,    (long)S_ * D_);
    conv(enc_W,        wb_enc,    (long)D_ * S_);

    // ======================= Encoder (fp32 — idx exactness) =======================
    gemm(states, S_, enc_W, S_, D_, (int)NTOK, se, D_, enc_b, nullptr, 0);
    embed_add<<<(int)NTOK, 256, 0, stream>>>(se, actions, act_emb, pos_emb, xbuf);

    for (int i = 0; i < L_; ++i) {
        gemm(xbuf, D_, enc_qkv_w + (long)i * 3 * D_ * D_, D_, 3 * D_, (int)NTOK,
             big, 3 * D_, enc_qkv_b + (long)i * 3 * D_, nullptr, 0);
        attn(big, big + D_, big + 2 * D_, bufa,
             (long)T_ * 3 * D_, 3 * D_, (long)T_ * 3 * D_, 3 * D_,
             (long)T_ * D_, D_, T_, T_, 0);
        gemm(bufa, D_, enc_out_w + (long)i * D_ * D_, D_, D_, (int)NTOK,
             bufb, D_, enc_out_b + i * D_, nullptr, 0);
        ln_res<<<(int)NTOK, 256, 0, stream>>>(xbuf, bufb, enc_ln1_g + i * D_, enc_ln1_b + i * D_, xbuf);
        gemm(xbuf, D_, enc_ff1_w + (long)i * DFF_ * D_, D_, DFF_, (int)NTOK,
             big, DFF_, enc_ff1_b + i * DFF_, nullptr, 1);
        gemm(big, DFF_, enc_ff2_w + (long)i * D_ * DFF_, DFF_, D_, (int)NTOK,
             bufb, D_, enc_ff2_b + i * D_, nullptr, 0);
        ln_res<<<(int)NTOK, 256, 0, stream>>>(xbuf, bufb, enc_ln2_g + i * D_, enc_ln2_b + i * D_, xbuf);
    }

    // ======================= VQ (fp32, numpy order) =======================
    row_sumsq<<<KC_, 256, 0, stream>>>(codebook, c2);
    gemm(xbuf, D_, codebook, D_, KC_, (int)NTOK, big, KC_, nullptr, nullptr, 0);
    vq_argmin<<<(int)NTOK, 256, 0, stream>>>(xbuf, big, c2, idx_i, idx_out);
    quant_build<<<(int)NTOK, 256, 0, stream>>>(idx_i, codebook, quant);
    zero_f<<<1, 1, 0, stream>>>(accum);
    sq_diff_partial<<<(int)NTOK, 256, 0, stream>>>(xbuf, quant, accum);
    loss_final<<<1, 1, 0, stream>>>(accum, loss_out);

    // ============ Decoder: precompute cross-attn K/V (bf16 MFMA) ============
    for (int i = 0; i < L_; ++i) {
        const unsigned short* wkv = wb_ca_qkv + (long)i * 3 * D_ * D_ + (long)D_ * D_;
        const float* bkv = dec_ca_qkv_b + (long)i * 3 * D_ + D_;
        gemmb(quant, D_, wkv, D_, 2 * D_, (int)NTOK,
              memKV + (long)i * NTOK * 2 * D_, 2 * D_, bkv, nullptr, 0, 0, 0);
    }
    cur0_init<<<B_, 256, 0, stream>>>(se, pos_emb, cur);

    // ============ Decoder: 19 autoregressive steps (bf16 split-K GEMMs) ============
    for (int t = 0; t < T_ - 1; ++t) {
        const int P = t + 1;
        const int M = B_ * P;
        assemble_y<<<M, 256, 0, stream>>>(cur, ybuf, P);

        for (int i = 0; i < L_; ++i) {
            // --- causal self-attention ---
            gemmb(ybuf, D_, wb_sa_qkv + (long)i * 3 * D_ * D_, D_, 3 * D_, M,
                  big, 3 * D_, dec_sa_qkv_b + (long)i * 3 * D_, nullptr, 0, 0, 0);
            attn(big, big + D_, big + 2 * D_, bufa,
                 (long)P * 3 * D_, 3 * D_, (long)P * 3 * D_, 3 * D_,
                 (long)P * D_, D_, P, P, 1);
            gemmb(bufa, D_, wb_sa_out + (long)i * D_ * D_, D_, D_, M,
                  bufb, D_, dec_sa_out_b + i * D_, nullptr, 0, 0, 0);
            ln_res<<<M, 256, 0, stream>>>(ybuf, bufb, dec_ln1_g + i * D_, dec_ln1_b + i * D_, ybuf);

            // --- cross-attention (memory fixed -> precomputed memKV) ---
            gemmb(ybuf, D_, wb_ca_qkv + (long)i * 3 * D_ * D_, D_, D_, M,
                  bufa, D_, dec_ca_qkv_b + (long)i * 3 * D_, nullptr, 0, 0, 0);
            const float* mkv = memKV + (long)i * NTOK * 2 * D_;
            attn(bufa, mkv, mkv + D_, big,
                 (long)P * D_, D_, (long)T_ * 2 * D_, 2 * D_,
                 (long)P * D_, D_, P, P, 0);
            gemmb(big, D_, wb_ca_out + (long)i * D_ * D_, D_, D_, M,
                  bufb, D_, dec_ca_out_b + i * D_, nullptr, 0, 0, 0);
            ln_res<<<M, 256, 0, stream>>>(ybuf, bufb, dec_ln2_g + i * D_, dec_ln2_b + i * D_, ybuf);

            // --- FFN (ff1 relu folded into ff2's A-read) ---
            gemmb(ybuf, D_, wb_ff1 + (long)i * DFF_ * D_, D_, DFF_, M,
                  big, DFF_, dec_ff1_b + i * DFF_, nullptr, 0, 0, 0);
            gemmb(big, DFF_, wb_ff2 + (long)i * D_ * DFF_, DFF_, D_, M,
                  bufb, D_, dec_ff2_b + i * D_, nullptr, 0, 1, 0);
            ln_res<<<M, 256, 0, stream>>>(ybuf, bufb, dec_ln3_g + i * D_, dec_ln3_b + i * D_, ybuf);
        }

        // preds[t] = y[:, -1] @ rec_W^T + rec_b  -> pred[:, t, :]  (strided C)
        gemmb(ybuf + (long)(P - 1) * D_, P * D_, wb_rec, D_, S_, B_,
              pred + (long)t * S_, (T_ - 1) * S_, rec_b, nullptr, 0, 0, 1);

        // dec_in[:, t+1] = preds[t] @ enc_W^T + enc_b + pos_emb[t+1]  (strided C)
        if (t < T_ - 2)
            gemmb(pred + (long)t * S_, (T_ - 1) * S_, wb_enc, S_, D_, B_,
                  cur + (long)(t + 1) * D_, T_ * D_, enc_b, pos_emb + (long)(t + 1) * D_,
                  0, 0, 1);
    }
}